// Round 11
// baseline (102.939 us; speedup 1.0000x reference)
//
#include <hip/hip_runtime.h>
#include <stdint.h>

#define BB 4
#define NN 4096
#define CC 256
#define DD 32

typedef __bf16 bf16;
typedef bf16 bf16x4 __attribute__((ext_vector_type(4)));
typedef bf16 bf16x8 __attribute__((ext_vector_type(8)));
typedef float f32x4 __attribute__((ext_vector_type(4)));
typedef unsigned int u32x4 __attribute__((ext_vector_type(4)));

__device__ __forceinline__ float fm3(float a, float b, float c) {
    return fmaxf(fmaxf(a, b), c);   // clang fuses to v_max3_f32
}

// ---------------- prepw: WT[320][256] = [Wq*log2e | Wk | Wv]^T (bf16) -------
__global__ void prepw_kernel(const float* __restrict__ Wq,
                             const float* __restrict__ Wk,
                             const float* __restrict__ Wv,
                             bf16* __restrict__ WT)
{
    int i = blockIdx.x * 256 + threadIdx.x;
    if (i < 320 * 256) {
        int d = i >> 8, c = i & 255;
        float val;
        if (d < DD)          val = Wq[c * DD + d] * 1.4426950408889634f;
        else if (d < 2 * DD) val = Wk[c * DD + (d - DD)];
        else                 val = Wv[c * CC + (d - 2 * DD)];
        WT[i] = (bf16)val;
    }
}

// ---------------- proj: [q|k|v] = x @ [Wq|Wk|Wv], f32 x read + in-reg cast --
__global__ __launch_bounds__(256) void proj_kernel(
    const float* __restrict__ x, const bf16* __restrict__ WT,
    bf16* __restrict__ qb, bf16* __restrict__ kb, bf16* __restrict__ vt)
{
    int b = blockIdx.x >> 7, nt = blockIdx.x & 127;   // 128 tiles of 32 rows
    int n0 = nt << 5;
    int tid = threadIdx.x;
    int w = tid >> 6, lane = tid & 63;
    int lm = lane & 15, g = lane >> 4;
    int rw = w >> 1;    // row half
    int ch = w & 1;     // ct half

    f32x4 acc[10];
    f32x4 zero4 = {0.f, 0.f, 0.f, 0.f};
#pragma unroll
    for (int i = 0; i < 10; ++i) acc[i] = zero4;

    const float* xrow = x + ((size_t)(b * NN) + n0 + rw * 16 + lm) * CC;
    for (int kc = 0; kc < 8; ++kc) {
        f32x4 a0 = *(const f32x4*)(xrow + kc * 32 + g * 8);
        f32x4 a1 = *(const f32x4*)(xrow + kc * 32 + g * 8 + 4);
        bf16x8 a;
        a[0] = (bf16)a0[0]; a[1] = (bf16)a0[1]; a[2] = (bf16)a0[2]; a[3] = (bf16)a0[3];
        a[4] = (bf16)a1[0]; a[5] = (bf16)a1[1]; a[6] = (bf16)a1[2]; a[7] = (bf16)a1[3];
#pragma unroll
        for (int ct = 0; ct < 10; ++ct) {
            int ctg = ch * 10 + ct;
            bf16x8 wv = *(const bf16x8*)(WT + (ctg * 16 + lm) * 256 + kc * 32 + g * 8);
            acc[ct] = __builtin_amdgcn_mfma_f32_16x16x32_bf16(a, wv, acc[ct], 0, 0, 0);
        }
    }

#pragma unroll
    for (int ct = 0; ct < 10; ++ct) {
        int ctg = ch * 10 + ct;
        int col = ctg * 16 + lm;
        if (ctg < 4) {
#pragma unroll
            for (int r = 0; r < 4; ++r) {
                int n = n0 + rw * 16 + g * 4 + r;
                bf16 hv = (bf16)acc[ct][r];
                if (ctg < 2) qb[((size_t)(b * NN) + n) * DD + col] = hv;
                else         kb[((size_t)(b * NN) + n) * DD + (col - DD)] = hv;
            }
        } else {
            int c = col - 64;
            int tile = nt >> 1;
            int nbase = ((nt & 1) * 32 + rw * 16 + g * 4) ^ ((c & 7) << 3);
            bf16x4 pk;
            pk[0] = (bf16)acc[ct][0]; pk[1] = (bf16)acc[ct][1];
            pk[2] = (bf16)acc[ct][2]; pk[3] = (bf16)acc[ct][3];
            size_t off = (((size_t)(b * 64 + tile)) * 256 + c) * 64 + nbase;
            *(bf16x4*)(vt + off) = pk;
        }
    }
}

// === attn v11: in-block split-K — 8 waves = 2 independent 4-wave pipelines ==
// Group grp (waves 4grp..4grp+3) handles keys [2048*grp, 2048*grp+2048) with
// the v10 monolith pipeline in its own 17 KB LDS slice. After the loops the
// groups exchange the acc half they don't own (bf16x4 via retired P buffers),
// plus wave-uniform m[4] and row l[64], merge with exp2(m-M) weights, and
// write the residual epilogue directly. No split-K partials, no combine pass.

#define LOADK(KT_, KF) { \
    const bf16* kbase_ = kb + ((size_t)(b * NN) + (size_t)(KT_) * 64) * DD + g * 8; \
    KF[0] = *(const bf16x8*)(kbase_ + (lm +  0) * DD); \
    KF[1] = *(const bf16x8*)(kbase_ + (lm + 16) * DD); \
    KF[2] = *(const bf16x8*)(kbase_ + (lm + 32) * DD); \
    KF[3] = *(const bf16x8*)(kbase_ + (lm + 48) * DD); }

#define LOADV(KT_, VB) { \
    const bf16* vtile_ = vt + ((size_t)(b * 64 + (KT_))) * 16384; \
    _Pragma("unroll") \
    for (int ct_ = 0; ct_ < 4; ++ct_) { \
        int c_ = 64 * wl + 16 * ct_ + lm; \
        const bf16* vrow_ = vtile_ + c_ * 64; \
        int vsw_ = (c_ & 7) << 3; \
        VB[ct_][0] = *(const bf16x8*)(vrow_ + ((8 * g) ^ vsw_)); \
        VB[ct_][1] = *(const bf16x8*)(vrow_ + ((32 + 8 * g) ^ vsw_)); \
    } }

#define PVBLOCK(PRV_, VB) { \
    const float* alph_p = (const float*)(glds + 16384 + (PRV_) * 512); \
    const uint32_t* flg_p = (const uint32_t*)(glds + 16384 + (PRV_) * 512 + 256); \
    const unsigned char* Pp_ = glds + (PRV_) * 8192; \
    u32x4 fl_ = *(const u32x4*)flg_p; \
    if ((fl_[0] & fl_[1] & fl_[2] & fl_[3]) == 0u) { \
        _Pragma("unroll") for (int rt_ = 0; rt_ < 4; ++rt_) { \
            f32x4 a_ = *(const f32x4*)(alph_p + rt_ * 16 + 4 * g); \
            _Pragma("unroll") for (int ct_ = 0; ct_ < 4; ++ct_) { \
                acc[rt_][ct_][0] *= a_[0]; acc[rt_][ct_][1] *= a_[1]; \
                acc[rt_][ct_][2] *= a_[2]; acc[rt_][ct_][3] *= a_[3]; \
            } \
        } \
    } \
    int psw_ = (lm & 7) << 4; \
    _Pragma("unroll") for (int rt_ = 0; rt_ < 4; ++rt_) { \
        const unsigned char* pr_ = Pp_ + (rt_ * 16 + lm) * 128; \
        bf16x8 pa0_ = *(const bf16x8*)(pr_ + (( 0 + 16 * g) ^ psw_)); \
        bf16x8 pa1_ = *(const bf16x8*)(pr_ + ((64 + 16 * g) ^ psw_)); \
        _Pragma("unroll") for (int ct_ = 0; ct_ < 4; ++ct_) { \
            acc[rt_][ct_] = __builtin_amdgcn_mfma_f32_16x16x32_bf16(pa0_, VB[ct_][0], acc[rt_][ct_], 0, 0, 0); \
            acc[rt_][ct_] = __builtin_amdgcn_mfma_f32_16x16x32_bf16(pa1_, VB[ct_][1], acc[rt_][ct_], 0, 0, 0); \
        } \
    } \
}

#define STEP(T_, KF, KFN, VBP, DOPV) { \
    const int cur_ = (T_) & 1; \
    __builtin_amdgcn_s_setprio(1); \
    f32x4 sv0 = __builtin_amdgcn_mfma_f32_16x16x32_bf16(KF[0], qf, zero4, 0, 0, 0); \
    f32x4 sv1 = __builtin_amdgcn_mfma_f32_16x16x32_bf16(KF[1], qf, zero4, 0, 0, 0); \
    f32x4 sv2 = __builtin_amdgcn_mfma_f32_16x16x32_bf16(KF[2], qf, zero4, 0, 0, 0); \
    f32x4 sv3 = __builtin_amdgcn_mfma_f32_16x16x32_bf16(KF[3], qf, zero4, 0, 0, 0); \
    int ktn_ = ((T_) + 1) & 63;   /* in-range by construction; garbage only when unused */ \
    LOADK(ktn_, KFN); \
    if (DOPV) { PVBLOCK(cur_ ^ 1, VBP); } \
    __builtin_amdgcn_s_setprio(0); \
    LOADV(ktn_, VBP); \
    float mxa_ = fm3(sv0[0], sv0[1], sv0[2]); \
    float mxb_ = fm3(sv0[3], sv1[0], sv1[1]); \
    float mxc_ = fm3(sv1[2], sv1[3], sv2[0]); \
    float mxd_ = fm3(sv2[1], sv2[2], sv2[3]); \
    float mxe_ = fm3(sv3[0], sv3[1], sv3[2]); \
    float mx_ = fmaxf(fm3(mxa_, mxb_, mxc_), fm3(mxd_, mxe_, sv3[3])); \
    float alpha_; \
    int wave_ok_ = __all(mx_ <= mrun + 11.5f); \
    if (!wave_ok_) { \
        float wm_ = mx_; \
        wm_ = fmaxf(wm_, __shfl_xor(wm_, 1)); \
        wm_ = fmaxf(wm_, __shfl_xor(wm_, 2)); \
        wm_ = fmaxf(wm_, __shfl_xor(wm_, 4)); \
        wm_ = fmaxf(wm_, __shfl_xor(wm_, 8)); \
        wm_ = fmaxf(wm_, __shfl_xor(wm_, 16)); \
        wm_ = fmaxf(wm_, __shfl_xor(wm_, 32)); \
        float mn_ = fmaxf(mrun, wm_); \
        alpha_ = __builtin_exp2f(mrun - mn_); \
        mrun = mn_; \
    } else alpha_ = 1.0f; \
    float ssum_; \
    { \
        _Pragma("unroll") for (int j_ = 0; j_ < 4; ++j_) sv0[j_] = __builtin_exp2f(sv0[j_] - mrun); \
        _Pragma("unroll") for (int j_ = 0; j_ < 4; ++j_) sv1[j_] = __builtin_exp2f(sv1[j_] - mrun); \
        _Pragma("unroll") for (int j_ = 0; j_ < 4; ++j_) sv2[j_] = __builtin_exp2f(sv2[j_] - mrun); \
        _Pragma("unroll") for (int j_ = 0; j_ < 4; ++j_) sv3[j_] = __builtin_exp2f(sv3[j_] - mrun); \
        f32x4 t_ = (sv0 + sv1) + (sv2 + sv3); \
        ssum_ = (t_[0] + t_[1]) + (t_[2] + t_[3]); \
    } \
    lrun = lrun * alpha_ + ssum_;  /* per-lane partial; reduced once after loop */ \
    unsigned char* Pb_ = glds + cur_ * 8192; \
    { \
        int rb_ = (16 * wl + lm) * 128; \
        int sw_ = (lm & 7) << 4; \
        bf16x4 pk_; \
        pk_[0] = (bf16)sv0[0]; pk_[1] = (bf16)sv0[1]; pk_[2] = (bf16)sv0[2]; pk_[3] = (bf16)sv0[3]; \
        *(bf16x4*)(Pb_ + rb_ + (( 0 + 8 * g) ^ sw_)) = pk_; \
        pk_[0] = (bf16)sv1[0]; pk_[1] = (bf16)sv1[1]; pk_[2] = (bf16)sv1[2]; pk_[3] = (bf16)sv1[3]; \
        *(bf16x4*)(Pb_ + rb_ + ((32 + 8 * g) ^ sw_)) = pk_; \
        pk_[0] = (bf16)sv2[0]; pk_[1] = (bf16)sv2[1]; pk_[2] = (bf16)sv2[2]; pk_[3] = (bf16)sv2[3]; \
        *(bf16x4*)(Pb_ + rb_ + ((64 + 8 * g) ^ sw_)) = pk_; \
        pk_[0] = (bf16)sv3[0]; pk_[1] = (bf16)sv3[1]; pk_[2] = (bf16)sv3[2]; pk_[3] = (bf16)sv3[3]; \
        *(bf16x4*)(Pb_ + rb_ + ((96 + 8 * g) ^ sw_)) = pk_; \
    } \
    float* alph_ = (float*)(glds + 16384 + cur_ * 512); \
    uint32_t* flg_ = (uint32_t*)(glds + 16384 + cur_ * 512 + 256); \
    if (g == 0) alph_[16 * wl + lm] = alpha_; \
    if (lane == 0) flg_[wl] = (uint32_t)wave_ok_; \
    asm volatile("s_waitcnt lgkmcnt(0)" ::: "memory"); \
    __builtin_amdgcn_s_barrier(); \
    asm volatile("" ::: "memory"); \
}

__global__ __launch_bounds__(512, 2) void attn_kernel(
    const bf16* __restrict__ qb, const bf16* __restrict__ kb,
    const bf16* __restrict__ vt, const float* __restrict__ x,
    const float* __restrict__ gamma, float* __restrict__ out)
{
    // two 17408-B pipeline slices: [grp][2x8KB P | 2x512B meta]
    __shared__ __align__(16) unsigned char lds[34816];
    int bid = blockIdx.x;
    // XCD-aware decode: batch b -> XCDs {2b,2b+1}; 256 blocks = 1/CU
    int xcd = bid & 7, slot = bid >> 3;          // slot in [0,32)
    int b = xcd >> 1;
    int qt = (xcd & 1) * 32 + slot;              // [0,64)
    int n0 = qt << 6;
    int tid = threadIdx.x;
    int w = tid >> 6, lane = tid & 63;
    int lm = lane & 15, g = lane >> 4;
    int grp = w >> 2;            // key-half group (SIMD s hosts wave s and s+4)
    int wl = w & 3;              // wave-in-group: QK row stripe + chan quarter
    unsigned char* glds = lds + grp * 17408;

    // Q fragment (MFMA B-operand: col=qrow=lm, k=8g..8g+7)
    bf16x8 qf = *(const bf16x8*)(qb + ((size_t)(b * NN) + n0 + wl * 16 + lm) * DD + g * 8);

    f32x4 acc[4][4]; // [row-tile][chan-tile], rows rt*16+4g+r, chans 64wl+16ct+lm
    f32x4 zero4 = {0.f, 0.f, 0.f, 0.f};
#pragma unroll
    for (int i = 0; i < 4; ++i)
#pragma unroll
        for (int j = 0; j < 4; ++j) acc[i][j] = zero4;
    float mrun = -1e30f, lrun = 0.f;

    int kt0 = grp * 32;
    int kt1 = kt0 + 32;

    bf16x8 kfA[4], kfB[4];
    bf16x8 vbA[4][2], vbB[4][2];
    LOADK(kt0, kfA);
    LOADV(kt0, vbA);

    STEP(kt0, kfA, kfB, vbB, 0);      // P(kt0) -> parity 0

    int kt = kt0 + 1;
    while (kt + 2 <= kt1) {
        STEP(kt,     kfB, kfA, vbA, 1);
        STEP(kt + 1, kfA, kfB, vbB, 1);
        kt += 2;
    }
    STEP(kt1 - 1, kfB, kfA, vbA, 1);  // kt1-1 odd
    PVBLOCK(1, vbB);                  // trailing PV: P(kt1-1) parity 1, V in vbB

    // row-total softmax denominator for this key-half
    lrun += __shfl_xor(lrun, 16);
    lrun += __shfl_xor(lrun, 32);

    // all trailing PV LDS reads are consumed (MFMA waits) — safe to retire P bufs
    asm volatile("s_waitcnt lgkmcnt(0)" ::: "memory");
    __builtin_amdgcn_s_barrier();
    asm volatile("" ::: "memory");

    // publish l[64], m[4] and export the acc half the other group will write
    float* lsh = (float*)(glds + 16384);         // l per row (this key-half)
    float* msh = (float*)(glds + 16384 + 256);   // m per 16-row stripe
    if (g == 0) lsh[16 * wl + lm] = lrun;
    if (lane == 0) msh[wl] = mrun;
    {
        unsigned char* xout = glds + wl * 4096;  // retired P region, 4KB/wave
        int rtbase = grp ? 0 : 2;                // grp0 exports rows 32-63, grp1 rows 0-31
#pragma unroll
        for (int rr = 0; rr < 2; ++rr) {
#pragma unroll
            for (int ct = 0; ct < 4; ++ct) {
                f32x4 a4 = acc[rtbase + rr][ct];
                bf16x4 p4;
                p4[0] = (bf16)a4[0]; p4[1] = (bf16)a4[1];
                p4[2] = (bf16)a4[2]; p4[3] = (bf16)a4[3];
                *(bf16x4*)(xout + ((rr * 4 + ct) * 64 + g * 16 + lm) * 8) = p4;
            }
        }
    }
    asm volatile("s_waitcnt lgkmcnt(0)" ::: "memory");
    __builtin_amdgcn_s_barrier();
    asm volatile("" ::: "memory");

    // merge + residual epilogue: grp0 writes rows 0-31, grp1 rows 32-63
    const unsigned char* oglds = lds + (grp ^ 1) * 17408;
    const unsigned char* xin = oglds + wl * 4096;
    const float* lo = (const float*)(oglds + 16384);
    const float* mo = (const float*)(oglds + 16384 + 256);
    float gam = gamma[0];
    int rself = grp ? 2 : 0;
#pragma unroll
    for (int rr = 0; rr < 2; ++rr) {
        int rt = rself + rr;                     // global 16-row stripe
        float mS = msh[rt], mO = mo[rt];
        float M = fmaxf(mS, mO);
        float wS = __builtin_exp2f(mS - M);
        float wO = __builtin_exp2f(mO - M);
        f32x4 lvS = *(const f32x4*)(lsh + rt * 16 + 4 * g);
        f32x4 lvO = *(const f32x4*)(lo + rt * 16 + 4 * g);
        f32x4 inv;
#pragma unroll
        for (int j = 0; j < 4; ++j) inv[j] = 1.f / (wS * lvS[j] + wO * lvO[j]);
#pragma unroll
        for (int ct = 0; ct < 4; ++ct) {
            int col = 64 * wl + 16 * ct + lm;
            bf16x4 ob = *(const bf16x4*)(xin + ((rr * 4 + ct) * 64 + g * 16 + lm) * 8);
#pragma unroll
            for (int r = 0; r < 4; ++r) {
                int n = n0 + rt * 16 + 4 * g + r;
                size_t idx = ((size_t)(b * NN) + n) * CC + col;
                float merged = wS * acc[rt][ct][r] + wO * (float)ob[r];
                out[idx] = x[idx] + gam * merged * inv[r];
            }
        }
    }
}

extern "C" void kernel_launch(void* const* d_in, const int* in_sizes, int n_in,
                              void* d_out, int out_size, void* d_ws, size_t ws_size,
                              hipStream_t stream)
{
    const float* x     = (const float*)d_in[0];
    const float* Wq    = (const float*)d_in[1];
    const float* Wk    = (const float*)d_in[2];
    const float* Wv    = (const float*)d_in[3];
    const float* gamma = (const float*)d_in[4];
    float* out = (float*)d_out;

    char* ws = (char*)d_ws;
    bf16* WT = (bf16*)(ws);                  //   163,840 B
    bf16* qb = (bf16*)(ws + 163840);         // 1,048,576 B
    bf16* kb = (bf16*)(ws + 1212416);        // 1,048,576 B
    bf16* vt = (bf16*)(ws + 2260992);        // 8,388,608 B  (end 10,649,600)

    hipLaunchKernelGGL(prepw_kernel, dim3(320), dim3(256), 0, stream,
                       Wq, Wk, Wv, WT);
    hipLaunchKernelGGL(proj_kernel, dim3(512), dim3(256), 0, stream,
                       x, WT, qb, kb, vt);
    hipLaunchKernelGGL(attn_kernel, dim3(256), dim3(512), 0, stream,
                       qb, kb, vt, x, gamma, out);
}

// Round 12
// 95.456 us; speedup vs baseline: 1.0784x; 1.0784x over previous
//
#include <hip/hip_runtime.h>
#include <stdint.h>

#define BB 4
#define NN 4096
#define CC 256
#define DD 32

typedef __bf16 bf16;
typedef bf16 bf16x4 __attribute__((ext_vector_type(4)));
typedef bf16 bf16x8 __attribute__((ext_vector_type(8)));
typedef float f32x4 __attribute__((ext_vector_type(4)));
typedef unsigned int u32x4 __attribute__((ext_vector_type(4)));

__device__ __forceinline__ float fm3(float a, float b, float c) {
    return fmaxf(fmaxf(a, b), c);   // clang fuses to v_max3_f32
}

// ---------------- prepw: WT[320][256] = [Wq*log2e | Wk | Wv]^T (bf16) -------
__global__ void prepw_kernel(const float* __restrict__ Wq,
                             const float* __restrict__ Wk,
                             const float* __restrict__ Wv,
                             bf16* __restrict__ WT)
{
    int i = blockIdx.x * 256 + threadIdx.x;
    if (i < 320 * 256) {
        int d = i >> 8, c = i & 255;
        float val;
        if (d < DD)          val = Wq[c * DD + d] * 1.4426950408889634f;
        else if (d < 2 * DD) val = Wk[c * DD + (d - DD)];
        else                 val = Wv[c * CC + (d - 2 * DD)];
        WT[i] = (bf16)val;
    }
}

// ---------------- proj: [q|k|v] = x @ [Wq|Wk|Wv], f32 x read + in-reg cast --
__global__ __launch_bounds__(256) void proj_kernel(
    const float* __restrict__ x, const bf16* __restrict__ WT,
    bf16* __restrict__ qb, bf16* __restrict__ kb, bf16* __restrict__ vt)
{
    int b = blockIdx.x >> 7, nt = blockIdx.x & 127;   // 128 tiles of 32 rows
    int n0 = nt << 5;
    int tid = threadIdx.x;
    int w = tid >> 6, lane = tid & 63;
    int lm = lane & 15, g = lane >> 4;
    int rw = w >> 1;    // row half
    int ch = w & 1;     // ct half

    f32x4 acc[10];
    f32x4 zero4 = {0.f, 0.f, 0.f, 0.f};
#pragma unroll
    for (int i = 0; i < 10; ++i) acc[i] = zero4;

    const float* xrow = x + ((size_t)(b * NN) + n0 + rw * 16 + lm) * CC;
    for (int kc = 0; kc < 8; ++kc) {
        f32x4 a0 = *(const f32x4*)(xrow + kc * 32 + g * 8);
        f32x4 a1 = *(const f32x4*)(xrow + kc * 32 + g * 8 + 4);
        bf16x8 a;
        a[0] = (bf16)a0[0]; a[1] = (bf16)a0[1]; a[2] = (bf16)a0[2]; a[3] = (bf16)a0[3];
        a[4] = (bf16)a1[0]; a[5] = (bf16)a1[1]; a[6] = (bf16)a1[2]; a[7] = (bf16)a1[3];
#pragma unroll
        for (int ct = 0; ct < 10; ++ct) {
            int ctg = ch * 10 + ct;
            bf16x8 wv = *(const bf16x8*)(WT + (ctg * 16 + lm) * 256 + kc * 32 + g * 8);
            acc[ct] = __builtin_amdgcn_mfma_f32_16x16x32_bf16(a, wv, acc[ct], 0, 0, 0);
        }
    }

#pragma unroll
    for (int ct = 0; ct < 10; ++ct) {
        int ctg = ch * 10 + ct;
        int col = ctg * 16 + lm;
        if (ctg < 4) {
#pragma unroll
            for (int r = 0; r < 4; ++r) {
                int n = n0 + rw * 16 + g * 4 + r;
                bf16 hv = (bf16)acc[ct][r];
                if (ctg < 2) qb[((size_t)(b * NN) + n) * DD + col] = hv;
                else         kb[((size_t)(b * NN) + n) * DD + (col - DD)] = hv;
            }
        } else {
            int c = col - 64;
            int tile = nt >> 1;
            int nbase = ((nt & 1) * 32 + rw * 16 + g * 4) ^ ((c & 7) << 3);
            bf16x4 pk;
            pk[0] = (bf16)acc[ct][0]; pk[1] = (bf16)acc[ct][1];
            pk[2] = (bf16)acc[ct][2]; pk[3] = (bf16)acc[ct][3];
            size_t off = (((size_t)(b * 64 + tile)) * 256 + c) * 64 + nbase;
            *(bf16x4*)(vt + off) = pk;
        }
    }
}

// === attn v12: v10 pipeline, single-buffered K/V regs -> 3 blocks/CU, KS=3 ==
// Lagged pipeline makes single-buffering safe: QK(t) consumes kf then kf is
// refilled with K(t+1) (one STEP of cover); PV(t-1) consumes vb then vb is
// refilled with V(t) (one STEP of cover). Unified reg demand ~140/wave
// (<=170) -> 3 waves/SIMD; grid 768 = 3 blocks/CU. All LDS layouts, P/V
// swizzles, softmax (wave-uniform deferred max, exp2 domain) identical to v10.

#define LOADK(KT_) { \
    const bf16* kbase_ = kb + ((size_t)(b * NN) + (size_t)(KT_) * 64) * DD + g * 8; \
    kf[0] = *(const bf16x8*)(kbase_ + (lm +  0) * DD); \
    kf[1] = *(const bf16x8*)(kbase_ + (lm + 16) * DD); \
    kf[2] = *(const bf16x8*)(kbase_ + (lm + 32) * DD); \
    kf[3] = *(const bf16x8*)(kbase_ + (lm + 48) * DD); }

#define LOADV(KT_) { \
    const bf16* vtile_ = vt + ((size_t)(b * 64 + (KT_))) * 16384; \
    _Pragma("unroll") \
    for (int ct_ = 0; ct_ < 4; ++ct_) { \
        int c_ = 64 * w + 16 * ct_ + lm; \
        const bf16* vrow_ = vtile_ + c_ * 64; \
        int vsw_ = (c_ & 7) << 3; \
        vb[ct_][0] = *(const bf16x8*)(vrow_ + ((8 * g) ^ vsw_)); \
        vb[ct_][1] = *(const bf16x8*)(vrow_ + ((32 + 8 * g) ^ vsw_)); \
    } }

// PV for tile whose P/alpha live in LDS parity PRV_ (runtime), V in vb.
#define PVBLOCK(PRV_) { \
    const float* alph_p = (const float*)(lds + 16384 + (PRV_) * 512); \
    const uint32_t* flg_p = (const uint32_t*)(lds + 16384 + (PRV_) * 512 + 256); \
    const unsigned char* Pp_ = lds + (PRV_) * 8192; \
    u32x4 fl_ = *(const u32x4*)flg_p; \
    if ((fl_[0] & fl_[1] & fl_[2] & fl_[3]) == 0u) { \
        _Pragma("unroll") for (int rt_ = 0; rt_ < 4; ++rt_) { \
            f32x4 a_ = *(const f32x4*)(alph_p + rt_ * 16 + 4 * g); \
            _Pragma("unroll") for (int ct_ = 0; ct_ < 4; ++ct_) { \
                acc[rt_][ct_][0] *= a_[0]; acc[rt_][ct_][1] *= a_[1]; \
                acc[rt_][ct_][2] *= a_[2]; acc[rt_][ct_][3] *= a_[3]; \
            } \
        } \
    } \
    int psw_ = (lm & 7) << 4; \
    __builtin_amdgcn_s_setprio(1); \
    _Pragma("unroll") for (int rt_ = 0; rt_ < 4; ++rt_) { \
        const unsigned char* pr_ = Pp_ + (rt_ * 16 + lm) * 128; \
        bf16x8 pa0_ = *(const bf16x8*)(pr_ + (( 0 + 16 * g) ^ psw_)); \
        bf16x8 pa1_ = *(const bf16x8*)(pr_ + ((64 + 16 * g) ^ psw_)); \
        _Pragma("unroll") for (int ct_ = 0; ct_ < 4; ++ct_) { \
            acc[rt_][ct_] = __builtin_amdgcn_mfma_f32_16x16x32_bf16(pa0_, vb[ct_][0], acc[rt_][ct_], 0, 0, 0); \
            acc[rt_][ct_] = __builtin_amdgcn_mfma_f32_16x16x32_bf16(pa1_, vb[ct_][1], acc[rt_][ct_], 0, 0, 0); \
        } \
    } \
    __builtin_amdgcn_s_setprio(0); \
}

// softmax + P/alpha/flag write + barrier for tile T_ (sv0..sv3 live)
#define SMTAIL(T_) { \
    const int cur_ = (T_) & 1; \
    float mxa_ = fm3(sv0[0], sv0[1], sv0[2]); \
    float mxb_ = fm3(sv0[3], sv1[0], sv1[1]); \
    float mxc_ = fm3(sv1[2], sv1[3], sv2[0]); \
    float mxd_ = fm3(sv2[1], sv2[2], sv2[3]); \
    float mxe_ = fm3(sv3[0], sv3[1], sv3[2]); \
    float mx_ = fmaxf(fm3(mxa_, mxb_, mxc_), fm3(mxd_, mxe_, sv3[3])); \
    float alpha_; \
    int wave_ok_ = __all(mx_ <= mrun + 11.5f); \
    if (!wave_ok_) { \
        float wm_ = mx_; \
        wm_ = fmaxf(wm_, __shfl_xor(wm_, 1)); \
        wm_ = fmaxf(wm_, __shfl_xor(wm_, 2)); \
        wm_ = fmaxf(wm_, __shfl_xor(wm_, 4)); \
        wm_ = fmaxf(wm_, __shfl_xor(wm_, 8)); \
        wm_ = fmaxf(wm_, __shfl_xor(wm_, 16)); \
        wm_ = fmaxf(wm_, __shfl_xor(wm_, 32)); \
        float mn_ = fmaxf(mrun, wm_); \
        alpha_ = __builtin_exp2f(mrun - mn_); \
        mrun = mn_; \
    } else alpha_ = 1.0f; \
    float ssum_; \
    { \
        _Pragma("unroll") for (int j_ = 0; j_ < 4; ++j_) sv0[j_] = __builtin_exp2f(sv0[j_] - mrun); \
        _Pragma("unroll") for (int j_ = 0; j_ < 4; ++j_) sv1[j_] = __builtin_exp2f(sv1[j_] - mrun); \
        _Pragma("unroll") for (int j_ = 0; j_ < 4; ++j_) sv2[j_] = __builtin_exp2f(sv2[j_] - mrun); \
        _Pragma("unroll") for (int j_ = 0; j_ < 4; ++j_) sv3[j_] = __builtin_exp2f(sv3[j_] - mrun); \
        f32x4 t_ = (sv0 + sv1) + (sv2 + sv3); \
        ssum_ = (t_[0] + t_[1]) + (t_[2] + t_[3]); \
    } \
    lrun = lrun * alpha_ + ssum_;  /* per-lane partial; reduced after loop */ \
    unsigned char* Pb_ = lds + cur_ * 8192; \
    { \
        int rb_ = (16 * w + lm) * 128; \
        int sw_ = (lm & 7) << 4; \
        bf16x4 pk_; \
        pk_[0] = (bf16)sv0[0]; pk_[1] = (bf16)sv0[1]; pk_[2] = (bf16)sv0[2]; pk_[3] = (bf16)sv0[3]; \
        *(bf16x4*)(Pb_ + rb_ + (( 0 + 8 * g) ^ sw_)) = pk_; \
        pk_[0] = (bf16)sv1[0]; pk_[1] = (bf16)sv1[1]; pk_[2] = (bf16)sv1[2]; pk_[3] = (bf16)sv1[3]; \
        *(bf16x4*)(Pb_ + rb_ + ((32 + 8 * g) ^ sw_)) = pk_; \
        pk_[0] = (bf16)sv2[0]; pk_[1] = (bf16)sv2[1]; pk_[2] = (bf16)sv2[2]; pk_[3] = (bf16)sv2[3]; \
        *(bf16x4*)(Pb_ + rb_ + ((64 + 8 * g) ^ sw_)) = pk_; \
        pk_[0] = (bf16)sv3[0]; pk_[1] = (bf16)sv3[1]; pk_[2] = (bf16)sv3[2]; pk_[3] = (bf16)sv3[3]; \
        *(bf16x4*)(Pb_ + rb_ + ((96 + 8 * g) ^ sw_)) = pk_; \
    } \
    float* alph_ = (float*)(lds + 16384 + cur_ * 512); \
    uint32_t* flg_ = (uint32_t*)(lds + 16384 + cur_ * 512 + 256); \
    if (g == 0) alph_[16 * w + lm] = alpha_; \
    if (lane == 0) flg_[w] = (uint32_t)wave_ok_; \
    asm volatile("s_waitcnt lgkmcnt(0)" ::: "memory"); \
    __builtin_amdgcn_s_barrier(); \
    asm volatile("" ::: "memory"); \
}

__global__ __launch_bounds__(256, 3) void attn_kernel(
    const bf16* __restrict__ qb, const bf16* __restrict__ kb,
    const bf16* __restrict__ vt, const float* __restrict__ x,
    const float* __restrict__ gamma, bf16* __restrict__ pacc,
    float* __restrict__ pml, float* __restrict__ out, int KS)
{
    // 2 x 8KB P buffers + 2 x 512B meta (alphas f32[64] @+0, flags u32[4] @+256)
    __shared__ __align__(16) unsigned char lds[17408];
    int bid = blockIdx.x;
    int b, qt, ks;
    if (KS == 3) {
        // XCD-aware decode: batch b -> XCDs {2b,2b+1} so vt/kb stay L2-resident
        int xcd = bid & 7, slot = bid >> 3;      // 768 blocks: slot in [0,96)
        b = xcd >> 1;
        int idx = (xcd & 1) * 96 + slot;         // [0,192) within batch
        qt = idx / 3; ks = idx - qt * 3;
    } else {
        ks = bid % KS; int t = bid / KS; b = t >> 6; qt = t & 63;
    }
    int bq = b * 64 + qt;
    int n0 = qt << 6;
    int tid = threadIdx.x;
    int w = tid >> 6, lane = tid & 63;
    int lm = lane & 15, g = lane >> 4;

    // Q fragment (MFMA B-operand: col=qrow=lm, k=8g..8g+7)
    bf16x8 qf = *(const bf16x8*)(qb + ((size_t)(b * NN) + n0 + w * 16 + lm) * DD + g * 8);

    f32x4 acc[4][4]; // [row-tile][chan-tile], rows rt*16+4g+r, chans 64w+16ct+lm
    f32x4 zero4 = {0.f, 0.f, 0.f, 0.f};
#pragma unroll
    for (int i = 0; i < 4; ++i)
#pragma unroll
        for (int j = 0; j < 4; ++j) acc[i][j] = zero4;
    float mrun = -1e30f, lrun = 0.f;

    int kt0 = (64 * ks) / KS;
    int kt1 = (64 * (ks + 1)) / KS;

    bf16x8 kf[4];          // single-buffered K (refilled after QK consumes it)
    bf16x8 vb[4][2];       // single-buffered V (refilled after PV consumes it)
    LOADK(kt0);
    LOADV(kt0);

    {   // first tile: QK(kt0), prefetch K(kt0+1); vb keeps V(kt0); no PV
        f32x4 sv0 = __builtin_amdgcn_mfma_f32_16x16x32_bf16(kf[0], qf, zero4, 0, 0, 0);
        f32x4 sv1 = __builtin_amdgcn_mfma_f32_16x16x32_bf16(kf[1], qf, zero4, 0, 0, 0);
        f32x4 sv2 = __builtin_amdgcn_mfma_f32_16x16x32_bf16(kf[2], qf, zero4, 0, 0, 0);
        f32x4 sv3 = __builtin_amdgcn_mfma_f32_16x16x32_bf16(kf[3], qf, zero4, 0, 0, 0);
        LOADK(kt0 + 1);
        SMTAIL(kt0);
    }

    for (int kt = kt0 + 1; kt < kt1; ++kt) {
        // QK(kt): kf holds K(kt), then refill with K(kt+1) (clamped; last is dummy)
        f32x4 sv0 = __builtin_amdgcn_mfma_f32_16x16x32_bf16(kf[0], qf, zero4, 0, 0, 0);
        f32x4 sv1 = __builtin_amdgcn_mfma_f32_16x16x32_bf16(kf[1], qf, zero4, 0, 0, 0);
        f32x4 sv2 = __builtin_amdgcn_mfma_f32_16x16x32_bf16(kf[2], qf, zero4, 0, 0, 0);
        f32x4 sv3 = __builtin_amdgcn_mfma_f32_16x16x32_bf16(kf[3], qf, zero4, 0, 0, 0);
        int ktn = (kt + 1) & 63;
        LOADK(ktn);
        // PV(kt-1): P/alpha parity (kt&1)^1, V(kt-1) in vb; then refill V(kt)
        PVBLOCK((kt & 1) ^ 1);
        LOADV(kt);
        SMTAIL(kt);
    }
    // trailing PV for last tile: parity (kt1-1)&1, V(kt1-1) in vb
    PVBLOCK((kt1 - 1) & 1);

    // row-total softmax denominator: reduce per-lane partials ONCE
    lrun += __shfl_xor(lrun, 16);
    lrun += __shfl_xor(lrun, 32);

    if (KS == 1) {
        __syncthreads();
        float* lsh = (float*)(lds + 16384);
        if (g == 0) lsh[16 * w + lm] = lrun;
        __syncthreads();
        float gam = gamma[0];
#pragma unroll
        for (int rt = 0; rt < 4; ++rt) {
            f32x4 lv = *(const f32x4*)(lsh + rt * 16 + 4 * g);
            f32x4 inv;
            inv[0] = 1.f / lv[0]; inv[1] = 1.f / lv[1];
            inv[2] = 1.f / lv[2]; inv[3] = 1.f / lv[3];
#pragma unroll
            for (int ct = 0; ct < 4; ++ct) {
                int col = 64 * w + 16 * ct + lm;
#pragma unroll
                for (int r = 0; r < 4; ++r) {
                    int n = n0 + rt * 16 + 4 * g + r;
                    size_t idx = ((size_t)(b * NN) + n) * CC + col;
                    out[idx] = x[idx] + gam * acc[rt][ct][r] * inv[r];
                }
            }
        }
    } else {
        bf16* pa = pacc + ((size_t)(bq * KS + ks)) * (64 * 256);
#pragma unroll
        for (int rt = 0; rt < 4; ++rt) {
#pragma unroll
            for (int ct = 0; ct < 4; ++ct) {
                int col = 64 * w + 16 * ct + lm;
#pragma unroll
                for (int r = 0; r < 4; ++r) {
                    int rowin = rt * 16 + 4 * g + r;
                    pa[rowin * 256 + col] = (bf16)acc[rt][ct][r];
                }
            }
        }
        if (g == 0) {
            int rowin = 16 * w + lm;
            size_t mo = ((size_t)(bq * KS + ks) * 64 + rowin) * 2;
            pml[mo + 0] = mrun;   // wave-uniform m (log2 domain)
            pml[mo + 1] = lrun;   // row total
        }
    }
}

// ---------------- combine: merge KS partials (bf16) + residual epilogue -----
// m/l are in log2 domain (Wq pre-scaled) -> exp2 weights.
__global__ __launch_bounds__(256) void combine_kernel(
    const bf16* __restrict__ pacc, const float* __restrict__ pml,
    const float* __restrict__ x, const float* __restrict__ gamma,
    float* __restrict__ out, int KS)
{
    int tid = threadIdx.x;
    int row = blockIdx.x * 4 + (tid >> 6);   // global row in [0, B*N)
    int lane = tid & 63;
    int bq = row >> 6;
    int r64 = row & 63;

    float m[4], l[4];
    float M = -3e38f;
    for (int ks = 0; ks < KS; ++ks) {
        size_t mo = ((size_t)(bq * KS + ks) * 64 + r64) * 2;
        m[ks] = pml[mo + 0];
        l[ks] = pml[mo + 1];
        M = fmaxf(M, m[ks]);
    }
    float L = 0.f;
    float wgt[4];
    for (int ks = 0; ks < KS; ++ks) {
        wgt[ks] = __builtin_exp2f(m[ks] - M);
        L += wgt[ks] * l[ks];
    }
    float s = gamma[0] / L;

    f32x4 a = {0.f, 0.f, 0.f, 0.f};
    for (int ks = 0; ks < KS; ++ks) {
        const bf16* pa = pacc + ((size_t)(bq * KS + ks) * 64 + r64) * 256;
        bf16x4 v = *(const bf16x4*)(pa + lane * 4);
        a[0] += wgt[ks] * (float)v[0]; a[1] += wgt[ks] * (float)v[1];
        a[2] += wgt[ks] * (float)v[2]; a[3] += wgt[ks] * (float)v[3];
    }
    const f32x4* xv = (const f32x4*)(x + (size_t)row * 256);
    f32x4 xi = xv[lane];
    f32x4 o;
    o[0] = xi[0] + s * a[0]; o[1] = xi[1] + s * a[1];
    o[2] = xi[2] + s * a[2]; o[3] = xi[3] + s * a[3];
    ((f32x4*)(out + (size_t)row * 256))[lane] = o;
}

extern "C" void kernel_launch(void* const* d_in, const int* in_sizes, int n_in,
                              void* d_out, int out_size, void* d_ws, size_t ws_size,
                              hipStream_t stream)
{
    const float* x     = (const float*)d_in[0];
    const float* Wq    = (const float*)d_in[1];
    const float* Wk    = (const float*)d_in[2];
    const float* Wv    = (const float*)d_in[3];
    const float* gamma = (const float*)d_in[4];
    float* out = (float*)d_out;

    char* ws = (char*)d_ws;
    bf16* WT = (bf16*)(ws);                  //   163,840 B
    bf16* qb = (bf16*)(ws + 163840);         // 1,048,576 B
    bf16* kb = (bf16*)(ws + 1212416);        // 1,048,576 B
    bf16* vt = (bf16*)(ws + 2260992);        // 8,388,608 B  (end 10,649,600)

    const size_t base = 10649600;
    // per-ks partials: acc = 256*64*256*2 B (bf16), ml = 256*64*2*4 B
    size_t need3 = base + (size_t)3 * (8388608 + 131072);
    int KS = (ws_size >= need3) ? 3 : 1;

    bf16*  pacc = (bf16*)(ws + base);
    float* pml  = (float*)(ws + base + (size_t)KS * 8388608);

    hipLaunchKernelGGL(prepw_kernel, dim3(320), dim3(256), 0, stream,
                       Wq, Wk, Wv, WT);
    hipLaunchKernelGGL(proj_kernel, dim3(512), dim3(256), 0, stream,
                       x, WT, qb, kb, vt);
    hipLaunchKernelGGL(attn_kernel, dim3(256 * KS), dim3(256), 0, stream,
                       qb, kb, vt, x, gamma, pacc, pml, out, KS);
    if (KS > 1) {
        hipLaunchKernelGGL(combine_kernel, dim3(BB * NN / 4), dim3(256), 0, stream,
                           pacc, pml, x, gamma, out, KS);
    }
}